// Round 3
// baseline (150.424 us; speedup 1.0000x reference)
//
#include <hip/hip_runtime.h>

// B=2, T=2048, C=1024, H=16, HD=64, SCALE=0.125
// Pipeline: cvt x->bf16; transpose W->bf16 [N][K]; GEMM1 qkv=x@Wqkv (bf16 out);
// transpose V part -> vT; flash attn (swapped-QK^T, O^T accum, unpaired q-tiles
// descending, double-buffered K/V, exp2-domain softmax, cvt_pk pack, defer-max)
// -> att (bf16); GEMM2 out = att@Wp + bp (f32).

typedef __attribute__((ext_vector_type(8))) short shortx8;
typedef __attribute__((ext_vector_type(4))) short shortx4;
typedef __attribute__((ext_vector_type(8))) unsigned short ushortx8;
typedef __attribute__((ext_vector_type(4))) float f32x4;

#define MFMA16(a, b, c) __builtin_amdgcn_mfma_f32_16x16x32_bf16((a), (b), (c), 0, 0, 0)

// SCALE * log2(e): softmax done in exp2 domain
#define SC_L2E 0.18033688011112042f

__device__ __forceinline__ unsigned short f2bf(float f) {
  union { float f; unsigned u; } v; v.f = f;
  unsigned r = v.u + 0x7fffu + ((v.u >> 16) & 1u);  // RNE; inputs finite
  return (unsigned short)(r >> 16);
}

__device__ __forceinline__ float fexp2(float x) {
#if __has_builtin(__builtin_amdgcn_exp2f)
  return __builtin_amdgcn_exp2f(x);
#else
  return exp2f(x);
#endif
}

__device__ __forceinline__ void gload16(const void* g, void* l) {
  __builtin_amdgcn_global_load_lds(
      (const __attribute__((address_space(1))) void*)g,
      (__attribute__((address_space(3))) void*)l, 16, 0, 0);
}

// ---------------- conversions ----------------
__global__ __launch_bounds__(256) void cvt_x(const float* __restrict__ x,
                                             unsigned short* __restrict__ xb, int n4) {
  int i = blockIdx.x * 256 + threadIdx.x;
  if (i < n4) {
    float4 v = ((const float4*)x)[i];
    unsigned short* o = xb + (size_t)i * 4;
    o[0] = f2bf(v.x); o[1] = f2bf(v.y); o[2] = f2bf(v.z); o[3] = f2bf(v.w);
  }
}

// 4x W [1024][1024] f32 -> WT [1024][1024] bf16 (WT[n][k] = W[k][n]); z picks matrix
__global__ __launch_bounds__(256) void transpose_w4(
    const float* __restrict__ Wq, const float* __restrict__ Wk,
    const float* __restrict__ Wv, const float* __restrict__ Wp,
    unsigned short* __restrict__ wqkvT, unsigned short* __restrict__ wpT) {
  __shared__ float tile[32][33];
  const int zi = blockIdx.z;
  const float* src = (zi == 0) ? Wq : (zi == 1) ? Wk : (zi == 2) ? Wv : Wp;
  unsigned short* dst = (zi == 3) ? wpT : wqkvT + (size_t)zi * 1048576;
  const int bx = blockIdx.x * 32, by = blockIdx.y * 32;
  const int tx = threadIdx.x & 31, ty = threadIdx.x >> 5;  // 32 x 8
  #pragma unroll
  for (int i = 0; i < 32; i += 8)
    tile[ty + i][tx] = src[(size_t)(by + ty + i) * 1024 + bx + tx];
  __syncthreads();
  #pragma unroll
  for (int i = 0; i < 32; i += 8)
    dst[(size_t)(bx + ty + i) * 1024 + by + tx] = f2bf(tile[tx][ty + i]);
}

// V part of qkv [4096][cols 2048..3071] bf16 -> vT [1024][4096] bf16
__global__ __launch_bounds__(256) void transpose_v(const unsigned short* __restrict__ qkv,
                                                   unsigned short* __restrict__ vT) {
  __shared__ unsigned short tile[64][65];
  const int bx = blockIdx.x * 64;  // hd dim (0..1023)
  const int by = blockIdx.y * 64;  // row dim (0..4095)
  const int t = threadIdx.x;
  const int r = t >> 3, c8 = (t & 7) << 3;
  #pragma unroll
  for (int i = 0; i < 2; ++i) {
    ushortx8 v = *(const ushortx8*)&qkv[(size_t)(by + i * 32 + r) * 3072 + 2048 + bx + c8];
    #pragma unroll
    for (int j = 0; j < 8; ++j) tile[i * 32 + r][c8 + j] = v[j];
  }
  __syncthreads();
  #pragma unroll
  for (int i = 0; i < 2; ++i) {
    const int dr = i * 32 + r;
    ushortx8 o;
    #pragma unroll
    for (int j = 0; j < 8; ++j) o[j] = tile[c8 + j][dr];
    *(ushortx8*)&vT[(size_t)(bx + dr) * 4096 + by + c8] = o;
  }
}

// ---------------- GEMM: C[M,N] = A[M,K] @ BT[N,K]^T ----------------
__global__ __launch_bounds__(256) void gemm_bt(
    const unsigned short* __restrict__ A, const unsigned short* __restrict__ BT,
    unsigned short* __restrict__ Cb, float* __restrict__ Cf,
    const float* __restrict__ bias, int M, int N, int K) {
  __shared__ unsigned short As[128 * 32];
  __shared__ unsigned short Bs[128 * 32];
  const int tid = threadIdx.x;
  const int lane = tid & 63, w = tid >> 6;
  const int wr = w >> 1, wc = w & 1;
  const int brow = blockIdx.y << 7, bcol = blockIdx.x << 7;

  f32x4 z = {0.f, 0.f, 0.f, 0.f};
  f32x4 acc[4][4];
  #pragma unroll
  for (int m = 0; m < 4; ++m)
    #pragma unroll
    for (int n = 0; n < 4; ++n) acc[m][n] = z;

  const int srow = tid >> 2;
  const int scol = (tid & 3) << 3;
  const unsigned short* Ap = A + (size_t)(brow + srow) * K + scol;
  const unsigned short* Bp = BT + (size_t)(bcol + srow) * K + scol;
  unsigned short* AsW = &As[w * 512];
  unsigned short* BsW = &Bs[w * 512];
  const size_t rowK64 = (size_t)64 * K;

  for (int k0 = 0; k0 < K; k0 += 32) {
    gload16(Ap + k0, AsW);
    gload16(Ap + rowK64 + k0, AsW + 2048);
    gload16(Bp + k0, BsW);
    gload16(Bp + rowK64 + k0, BsW + 2048);
    __syncthreads();
    shortx8 af[4], bf[4];
    const int koff = (lane >> 4) << 3;
    const int ar = (wr << 6) + (lane & 15);
    const int br = (wc << 6) + (lane & 15);
    #pragma unroll
    for (int m = 0; m < 4; ++m) af[m] = *(const shortx8*)&As[(ar + m * 16) * 32 + koff];
    #pragma unroll
    for (int n = 0; n < 4; ++n) bf[n] = *(const shortx8*)&Bs[(br + n * 16) * 32 + koff];
    #pragma unroll
    for (int m = 0; m < 4; ++m)
      #pragma unroll
      for (int n = 0; n < 4; ++n) acc[m][n] = MFMA16(af[m], bf[n], acc[m][n]);
    __syncthreads();
  }

  const int r0 = (lane >> 4) << 2;
  const int c0 = lane & 15;
  if (Cb) {
    #pragma unroll
    for (int m = 0; m < 4; ++m)
      #pragma unroll
      for (int n = 0; n < 4; ++n)
        #pragma unroll
        for (int j = 0; j < 4; ++j) {
          const size_t row = brow + (wr << 6) + m * 16 + r0 + j;
          const size_t col = bcol + (wc << 6) + n * 16 + c0;
          Cb[row * N + col] = f2bf(acc[m][n][j]);
        }
  } else {
    #pragma unroll
    for (int m = 0; m < 4; ++m)
      #pragma unroll
      for (int n = 0; n < 4; ++n)
        #pragma unroll
        for (int j = 0; j < 4; ++j) {
          const size_t row = brow + (wr << 6) + m * 16 + r0 + j;
          const size_t col = bcol + (wc << 6) + n * 16 + c0;
          Cf[row * N + col] = acc[m][n][j] + bias[col];
        }
  }
}

// ---------------- flash attention v3 ----------------
// Swapped QK^T: s = mfma(K_frag, Q_frag) -> S^T[kv][q]; lane owns ONE q column
// (q = lane&15; 4 lane-groups share it -> 2 shfl for max/sum). PV as
// O^T = mfma(V^T_frag, P^T_frag): m/l/alpha per-lane scalars. exp2 domain,
// cvt_pk bf16 pack, defer-max (THR=8 log2). One 64-row q-tile per block
// (descending size for load balance), K/V double-buffered, counted vmcnt.

template <bool MASK>
__device__ __forceinline__ void attn_tile(
    const unsigned short* __restrict__ K, const unsigned short* __restrict__ V,
    unsigned short* __restrict__ PsW,
    shortx8 qf0, shortx8 qf1, int lane, int kv0, int qrow,
    float& m_run, float& l_run, f32x4* acc) {
  const f32x4 z = {0.f, 0.f, 0.f, 0.f};
  const int ql = lane & 15, g = lane >> 4, swz = lane & 7;

  f32x4 s[4];
  #pragma unroll
  for (int f = 0; f < 4; ++f) {
    const int r = 16 * f + ql;
    shortx8 k0 = *(const shortx8*)&K[r * 64 + (((g) ^ swz) << 3)];
    shortx8 k1 = *(const shortx8*)&K[r * 64 + (((4 + g) ^ swz) << 3)];
    f32x4 t = MFMA16(k0, qf0, z);
    s[f] = MFMA16(k1, qf1, t);
  }

  float sv[16];
  #pragma unroll
  for (int f = 0; f < 4; ++f)
    #pragma unroll
    for (int j = 0; j < 4; ++j) {
      float v = s[f][j] * SC_L2E;
      if (MASK && (kv0 + 16 * f + 4 * g + j > qrow)) v = -__builtin_inff();
      sv[f * 4 + j] = v;
    }
  // pairwise max tree (depth 4)
  float m8[8], m4[4];
  #pragma unroll
  for (int i = 0; i < 8; ++i) m8[i] = fmaxf(sv[2 * i], sv[2 * i + 1]);
  #pragma unroll
  for (int i = 0; i < 4; ++i) m4[i] = fmaxf(m8[2 * i], m8[2 * i + 1]);
  float mx = fmaxf(fmaxf(m4[0], m4[1]), fmaxf(m4[2], m4[3]));
  mx = fmaxf(mx, __shfl_xor(mx, 16));
  mx = fmaxf(mx, __shfl_xor(mx, 32));

  if (!__all(mx <= m_run + 8.0f)) {  // defer-max: P bounded by 2^8
    const float nm = fmaxf(m_run, mx);
    const float alpha = fexp2(m_run - nm);
    #pragma unroll
    for (int c = 0; c < 4; ++c) acc[c] *= alpha;
    l_run *= alpha;
    m_run = nm;
  }

  float p[16];
  #pragma unroll
  for (int i = 0; i < 16; ++i) p[i] = fexp2(sv[i] - m_run);
  float s8[8], s4[4];
  #pragma unroll
  for (int i = 0; i < 8; ++i) s8[i] = p[2 * i] + p[2 * i + 1];
  #pragma unroll
  for (int i = 0; i < 4; ++i) s4[i] = s8[2 * i] + s8[2 * i + 1];
  float rsum = (s4[0] + s4[1]) + (s4[2] + s4[3]);
  rsum += __shfl_xor(rsum, 16);
  rsum += __shfl_xor(rsum, 32);
  l_run += rsum;

  // P^T -> Ps chunk-major [chunk8][ql16][8e]; lane holds kv 16f+4g+j
  #pragma unroll
  for (int f = 0; f < 4; ++f) {
    unsigned lo, hi;
    asm("v_cvt_pk_bf16_f32 %0, %1, %2" : "=v"(lo) : "v"(p[4 * f + 0]), "v"(p[4 * f + 1]));
    asm("v_cvt_pk_bf16_f32 %0, %1, %2" : "=v"(hi) : "v"(p[4 * f + 2]), "v"(p[4 * f + 3]));
    uint2 u; u.x = lo; u.y = hi;
    *(uint2*)&PsW[(2 * f + (g >> 1)) * 128 + ql * 8 + (g & 1) * 4] = u;
  }
  __builtin_amdgcn_sched_barrier(0);  // keep same-wave DS write before read
  shortx8 pf0 = *(const shortx8*)&PsW[(g) * 128 + ql * 8];
  shortx8 pf1 = *(const shortx8*)&PsW[(4 + g) * 128 + ql * 8];
  #pragma unroll
  for (int c = 0; c < 4; ++c) {
    const int r = 16 * c + ql;
    shortx8 v0 = *(const shortx8*)&V[r * 64 + (((g) ^ swz) << 3)];
    shortx8 v1 = *(const shortx8*)&V[r * 64 + (((4 + g) ^ swz) << 3)];
    acc[c] = MFMA16(v0, pf0, acc[c]);
    acc[c] = MFMA16(v1, pf1, acc[c]);
  }
}

__global__ __launch_bounds__(256) void attn_fwd(
    const unsigned short* __restrict__ qkv, const unsigned short* __restrict__ vT,
    unsigned short* __restrict__ att) {
  __shared__ unsigned short Ks[2][4096];
  __shared__ unsigned short Vt[2][4096];
  __shared__ unsigned short Ps[4][1024];

  const int tid = threadIdx.x;
  const int lane = tid & 63;
  const int w = tid >> 6;
  const int qt = 31 - blockIdx.x;  // descending work: big blocks dispatch first
  const int h = blockIdx.y, b = blockIdx.z;
  const int ql = lane & 15, g = lane >> 4;
  const int qrow = qt * 64 + w * 16 + ql;
  unsigned short* PsW = &Ps[w][0];

  // Q fragment (MFMA B-operand): Q[q=lane&15][d=(lane>>4)*8+e]
  const unsigned short* qp = qkv + ((size_t)(b * 2048 + qrow)) * 3072 + h * 64 + (g << 3);
  const shortx8 qf0 = *(const shortx8*)qp;
  const shortx8 qf1 = *(const shortx8*)(qp + 32);

  f32x4 z = {0.f, 0.f, 0.f, 0.f};
  f32x4 acc[4];
  #pragma unroll
  for (int c = 0; c < 4; ++c) acc[c] = z;
  float m_run = -__builtin_inff(), l_run = 0.f;

  // staging: thread t -> row t>>3 (+32 second half), src 16B chunk (t&7)^(row&7)
  const int srow = tid >> 3;
  const int sch = ((tid & 7) ^ (srow & 7)) << 3;
  const unsigned short* kb = qkv + ((size_t)(b * 2048 + srow)) * 3072 + 1024 + h * 64 + sch;
  const unsigned short* vb = vT + ((size_t)(h * 64 + srow)) * 4096 + b * 2048 + sch;

  #define STAGE(kv0_, bufi_)                                        \
    do {                                                            \
      unsigned short* Kd = &Ks[bufi_][w * 512];                     \
      unsigned short* Vd = &Vt[bufi_][w * 512];                     \
      gload16(kb + (size_t)(kv0_) * 3072, Kd);                      \
      gload16(kb + (size_t)((kv0_) + 32) * 3072, Kd + 2048);        \
      gload16(vb + (kv0_), Vd);                                     \
      gload16(vb + (size_t)32 * 4096 + (kv0_), Vd + 2048);          \
    } while (0)

  int buf = 0;
  STAGE(0, 0);
  for (int kvt = 0; kvt <= qt; ++kvt) {
    const bool last = (kvt == qt);
    if (!last) STAGE((kvt + 1) * 64, buf ^ 1);
    if (last) asm volatile("s_waitcnt vmcnt(0)" ::: "memory");
    else      asm volatile("s_waitcnt vmcnt(4)" ::: "memory");
    __builtin_amdgcn_sched_barrier(0);
    __builtin_amdgcn_s_barrier();
    __builtin_amdgcn_sched_barrier(0);
    const unsigned short* K = Ks[buf];
    const unsigned short* V = Vt[buf];
    if (last)
      attn_tile<true>(K, V, PsW, qf0, qf1, lane, kvt * 64, qrow, m_run, l_run, acc);
    else
      attn_tile<false>(K, V, PsW, qf0, qf1, lane, kvt * 64, qrow, m_run, l_run, acc);
    __builtin_amdgcn_sched_barrier(0);
    __builtin_amdgcn_s_barrier();
    __builtin_amdgcn_sched_barrier(0);
    buf ^= 1;
  }
  #undef STAGE

  // epilogue: acc[c][j] = O^T[d=16c+4g+j][q=qrow]; pack 4 consecutive d -> 8B store
  const float inv = 1.f / l_run;
  unsigned short* o = att + ((size_t)(b * 2048 + qrow)) * 1024 + h * 64 + 4 * g;
  #pragma unroll
  for (int c = 0; c < 4; ++c) {
    shortx4 a;
    #pragma unroll
    for (int j = 0; j < 4; ++j) a[j] = (short)f2bf(acc[c][j] * inv);
    *(shortx4*)&o[16 * c] = a;
  }
}

// ---------------- launch ----------------
extern "C" void kernel_launch(void* const* d_in, const int* in_sizes, int n_in,
                              void* d_out, int out_size, void* d_ws, size_t ws_size,
                              hipStream_t stream) {
  const float* x  = (const float*)d_in[0];
  const float* Wq = (const float*)d_in[1];
  const float* Wk = (const float*)d_in[2];
  const float* Wv = (const float*)d_in[3];
  const float* Wp = (const float*)d_in[4];
  const float* bp = (const float*)d_in[5];

  char* ws = (char*)d_ws;
  unsigned short* xb    = (unsigned short*)(ws);                        //  8 MB [4096][1024]
  unsigned short* wqkvT = (unsigned short*)(ws + (size_t)8  * 1048576); //  6 MB [3072][1024]
  unsigned short* wpT   = (unsigned short*)(ws + (size_t)14 * 1048576); //  2 MB [1024][1024]
  unsigned short* qkv   = (unsigned short*)(ws + (size_t)16 * 1048576); // 24 MB [4096][3072]
  unsigned short* vT    = (unsigned short*)(ws + (size_t)40 * 1048576); //  8 MB [1024][4096]
  unsigned short* att   = (unsigned short*)(ws + (size_t)48 * 1048576); //  8 MB [4096][1024]

  cvt_x<<<dim3(4096), dim3(256), 0, stream>>>(x, xb, 1048576);
  transpose_w4<<<dim3(32, 32, 4), dim3(256), 0, stream>>>(Wq, Wk, Wv, Wp, wqkvT, wpT);
  gemm_bt<<<dim3(24, 32), dim3(256), 0, stream>>>(xb, wqkvT, qkv, nullptr, nullptr,
                                                  4096, 3072, 1024);
  transpose_v<<<dim3(16, 64), dim3(256), 0, stream>>>(qkv, vT);
  attn_fwd<<<dim3(32, 16, 2), dim3(256), 0, stream>>>(qkv, vT, att);
  gemm_bt<<<dim3(8, 32), dim3(256), 0, stream>>>(att, wpT, nullptr, (float*)d_out, bp,
                                                 4096, 1024, 1024);
}

// Round 4
// 142.874 us; speedup vs baseline: 1.0528x; 1.0528x over previous
//
#include <hip/hip_runtime.h>

// B=2, T=2048, C=1024, H=16, HD=64, SCALE=0.125
// Pipeline: cvt x->bf16; transpose W->bf16 [N][K]; GEMM1 qkv=x@Wqkv (bf16 out);
// transpose V part -> vT; flash attn v4 (swapped-QK^T, O^T accum, 32 q-rows/wave,
// 2-wave blocks, shared K/V frags, XCD-aware grid, double-buffered K/V, exp2
// softmax, cvt_pk, defer-max) -> att (bf16); GEMM2 out = att@Wp + bp (f32).

typedef __attribute__((ext_vector_type(8))) short shortx8;
typedef __attribute__((ext_vector_type(4))) short shortx4;
typedef __attribute__((ext_vector_type(8))) unsigned short ushortx8;
typedef __attribute__((ext_vector_type(4))) float f32x4;

#define MFMA16(a, b, c) __builtin_amdgcn_mfma_f32_16x16x32_bf16((a), (b), (c), 0, 0, 0)

// SCALE * log2(e): softmax done in exp2 domain
#define SC_L2E 0.18033688011112042f

__device__ __forceinline__ unsigned short f2bf(float f) {
  union { float f; unsigned u; } v; v.f = f;
  unsigned r = v.u + 0x7fffu + ((v.u >> 16) & 1u);  // RNE; inputs finite
  return (unsigned short)(r >> 16);
}

__device__ __forceinline__ float fexp2(float x) {
#if __has_builtin(__builtin_amdgcn_exp2f)
  return __builtin_amdgcn_exp2f(x);
#else
  return exp2f(x);
#endif
}

__device__ __forceinline__ void gload16(const void* g, void* l) {
  __builtin_amdgcn_global_load_lds(
      (const __attribute__((address_space(1))) void*)g,
      (__attribute__((address_space(3))) void*)l, 16, 0, 0);
}

// ---------------- conversions ----------------
__global__ __launch_bounds__(256) void cvt_x(const float* __restrict__ x,
                                             unsigned short* __restrict__ xb, int n4) {
  int i = blockIdx.x * 256 + threadIdx.x;
  if (i < n4) {
    float4 v = ((const float4*)x)[i];
    unsigned short* o = xb + (size_t)i * 4;
    o[0] = f2bf(v.x); o[1] = f2bf(v.y); o[2] = f2bf(v.z); o[3] = f2bf(v.w);
  }
}

// 4x W [1024][1024] f32 -> WT [1024][1024] bf16 (WT[n][k] = W[k][n]); z picks matrix
__global__ __launch_bounds__(256) void transpose_w4(
    const float* __restrict__ Wq, const float* __restrict__ Wk,
    const float* __restrict__ Wv, const float* __restrict__ Wp,
    unsigned short* __restrict__ wqkvT, unsigned short* __restrict__ wpT) {
  __shared__ float tile[32][33];
  const int zi = blockIdx.z;
  const float* src = (zi == 0) ? Wq : (zi == 1) ? Wk : (zi == 2) ? Wv : Wp;
  unsigned short* dst = (zi == 3) ? wpT : wqkvT + (size_t)zi * 1048576;
  const int bx = blockIdx.x * 32, by = blockIdx.y * 32;
  const int tx = threadIdx.x & 31, ty = threadIdx.x >> 5;  // 32 x 8
  #pragma unroll
  for (int i = 0; i < 32; i += 8)
    tile[ty + i][tx] = src[(size_t)(by + ty + i) * 1024 + bx + tx];
  __syncthreads();
  #pragma unroll
  for (int i = 0; i < 32; i += 8)
    dst[(size_t)(bx + ty + i) * 1024 + by + tx] = f2bf(tile[tx][ty + i]);
}

// V part of qkv [4096][cols 2048..3071] bf16 -> vT [1024][4096] bf16
__global__ __launch_bounds__(256) void transpose_v(const unsigned short* __restrict__ qkv,
                                                   unsigned short* __restrict__ vT) {
  __shared__ unsigned short tile[64][65];
  const int bx = blockIdx.x * 64;  // hd dim (0..1023)
  const int by = blockIdx.y * 64;  // row dim (0..4095)
  const int t = threadIdx.x;
  const int r = t >> 3, c8 = (t & 7) << 3;
  #pragma unroll
  for (int i = 0; i < 2; ++i) {
    ushortx8 v = *(const ushortx8*)&qkv[(size_t)(by + i * 32 + r) * 3072 + 2048 + bx + c8];
    #pragma unroll
    for (int j = 0; j < 8; ++j) tile[i * 32 + r][c8 + j] = v[j];
  }
  __syncthreads();
  #pragma unroll
  for (int i = 0; i < 2; ++i) {
    const int dr = i * 32 + r;
    ushortx8 o;
    #pragma unroll
    for (int j = 0; j < 8; ++j) o[j] = tile[c8 + j][dr];
    *(ushortx8*)&vT[(size_t)(bx + dr) * 4096 + by + c8] = o;
  }
}

// ---------------- GEMM: C[M,N] = A[M,K] @ BT[N,K]^T ----------------
__global__ __launch_bounds__(256) void gemm_bt(
    const unsigned short* __restrict__ A, const unsigned short* __restrict__ BT,
    unsigned short* __restrict__ Cb, float* __restrict__ Cf,
    const float* __restrict__ bias, int M, int N, int K) {
  __shared__ unsigned short As[128 * 32];
  __shared__ unsigned short Bs[128 * 32];
  const int tid = threadIdx.x;
  const int lane = tid & 63, w = tid >> 6;
  const int wr = w >> 1, wc = w & 1;
  const int brow = blockIdx.y << 7, bcol = blockIdx.x << 7;

  f32x4 z = {0.f, 0.f, 0.f, 0.f};
  f32x4 acc[4][4];
  #pragma unroll
  for (int m = 0; m < 4; ++m)
    #pragma unroll
    for (int n = 0; n < 4; ++n) acc[m][n] = z;

  const int srow = tid >> 2;
  const int scol = (tid & 3) << 3;
  const unsigned short* Ap = A + (size_t)(brow + srow) * K + scol;
  const unsigned short* Bp = BT + (size_t)(bcol + srow) * K + scol;
  unsigned short* AsW = &As[w * 512];
  unsigned short* BsW = &Bs[w * 512];
  const size_t rowK64 = (size_t)64 * K;

  for (int k0 = 0; k0 < K; k0 += 32) {
    gload16(Ap + k0, AsW);
    gload16(Ap + rowK64 + k0, AsW + 2048);
    gload16(Bp + k0, BsW);
    gload16(Bp + rowK64 + k0, BsW + 2048);
    __syncthreads();
    shortx8 af[4], bf[4];
    const int koff = (lane >> 4) << 3;
    const int ar = (wr << 6) + (lane & 15);
    const int br = (wc << 6) + (lane & 15);
    #pragma unroll
    for (int m = 0; m < 4; ++m) af[m] = *(const shortx8*)&As[(ar + m * 16) * 32 + koff];
    #pragma unroll
    for (int n = 0; n < 4; ++n) bf[n] = *(const shortx8*)&Bs[(br + n * 16) * 32 + koff];
    #pragma unroll
    for (int m = 0; m < 4; ++m)
      #pragma unroll
      for (int n = 0; n < 4; ++n) acc[m][n] = MFMA16(af[m], bf[n], acc[m][n]);
    __syncthreads();
  }

  const int r0 = (lane >> 4) << 2;
  const int c0 = lane & 15;
  if (Cb) {
    #pragma unroll
    for (int m = 0; m < 4; ++m)
      #pragma unroll
      for (int n = 0; n < 4; ++n)
        #pragma unroll
        for (int j = 0; j < 4; ++j) {
          const size_t row = brow + (wr << 6) + m * 16 + r0 + j;
          const size_t col = bcol + (wc << 6) + n * 16 + c0;
          Cb[row * N + col] = f2bf(acc[m][n][j]);
        }
  } else {
    #pragma unroll
    for (int m = 0; m < 4; ++m)
      #pragma unroll
      for (int n = 0; n < 4; ++n)
        #pragma unroll
        for (int j = 0; j < 4; ++j) {
          const size_t row = brow + (wr << 6) + m * 16 + r0 + j;
          const size_t col = bcol + (wc << 6) + n * 16 + c0;
          Cf[row * N + col] = acc[m][n][j] + bias[col];
        }
  }
}

// ---------------- flash attention v4 ----------------
// 2 waves/block, 32 q-rows/wave (two 16-row sub-tiles A,B sharing K/V frags).
// Swapped QK^T: s = mfma(K,Q) -> S^T, lane owns q-col ql; softmax per-lane with
// 2 shfls each for max/sum. PV: O^T = mfma(V^T, P^T). exp2 domain, cvt_pk pack,
// defer-max. K/V [64][64] LDS tiles double-buffered, XOR-swizzled via source.

__device__ __forceinline__ void softmax_pack(
    const f32x4* s, unsigned short* PsS, int ql, int g, int kv0, int qrow,
    bool mask, float& m_run, float& l_run, f32x4* acc) {
  float sv[16];
  #pragma unroll
  for (int f = 0; f < 4; ++f)
    #pragma unroll
    for (int j = 0; j < 4; ++j) sv[f * 4 + j] = s[f][j] * SC_L2E;
  if (mask) {
    #pragma unroll
    for (int f = 0; f < 4; ++f)
      #pragma unroll
      for (int j = 0; j < 4; ++j)
        if (kv0 + 16 * f + 4 * g + j > qrow) sv[f * 4 + j] = -__builtin_inff();
  }
  float m8[8], m4[4];
  #pragma unroll
  for (int i = 0; i < 8; ++i) m8[i] = fmaxf(sv[2 * i], sv[2 * i + 1]);
  #pragma unroll
  for (int i = 0; i < 4; ++i) m4[i] = fmaxf(m8[2 * i], m8[2 * i + 1]);
  float mx = fmaxf(fmaxf(m4[0], m4[1]), fmaxf(m4[2], m4[3]));
  mx = fmaxf(mx, __shfl_xor(mx, 16));
  mx = fmaxf(mx, __shfl_xor(mx, 32));

  if (!__all(mx <= m_run + 8.0f)) {  // defer-max: P bounded by 2^8
    const float nm = fmaxf(m_run, mx);
    const float alpha = fexp2(m_run - nm);
    #pragma unroll
    for (int c = 0; c < 4; ++c) acc[c] *= alpha;
    l_run *= alpha;
    m_run = nm;
  }

  float p[16];
  #pragma unroll
  for (int i = 0; i < 16; ++i) p[i] = fexp2(sv[i] - m_run);
  float s8[8], s4[4];
  #pragma unroll
  for (int i = 0; i < 8; ++i) s8[i] = p[2 * i] + p[2 * i + 1];
  #pragma unroll
  for (int i = 0; i < 4; ++i) s4[i] = s8[2 * i] + s8[2 * i + 1];
  float rsum = (s4[0] + s4[1]) + (s4[2] + s4[3]);
  rsum += __shfl_xor(rsum, 16);
  rsum += __shfl_xor(rsum, 32);
  l_run += rsum;

  // P^T -> Ps chunk-major [chunk8][ql16][8e]; lane holds kv 16f+4g+j
  #pragma unroll
  for (int f = 0; f < 4; ++f) {
    unsigned lo, hi;
    asm("v_cvt_pk_bf16_f32 %0, %1, %2" : "=v"(lo) : "v"(p[4 * f + 0]), "v"(p[4 * f + 1]));
    asm("v_cvt_pk_bf16_f32 %0, %1, %2" : "=v"(hi) : "v"(p[4 * f + 2]), "v"(p[4 * f + 3]));
    uint2 u; u.x = lo; u.y = hi;
    *(uint2*)&PsS[(2 * f + (g >> 1)) * 128 + ql * 8 + (g & 1) * 4] = u;
  }
}

__global__ __launch_bounds__(128) void attn_fwd(
    const unsigned short* __restrict__ qkv, const unsigned short* __restrict__ vT,
    unsigned short* __restrict__ att) {
  __shared__ unsigned short Ks[2][4096];
  __shared__ unsigned short Vt[2][4096];
  __shared__ unsigned short Ps[2][2][1024];  // [wave][sub][chunk8*16ql*8e]

  const int tid = threadIdx.x;
  const int lane = tid & 63;
  const int w = tid >> 6;                       // 2 waves
  const int hb = blockIdx.x;                    // h,b -> same XCD per stream
  const int h = hb & 15, b = hb >> 4;
  const int qt = 31 - blockIdx.y;               // descending work
  const int ql = lane & 15, g = lane >> 4;
  const int swz = ql & 7;
  const int qbase = qt * 64 + w * 32;
  const int qrowA = qbase + ql;
  const int qrowB = qbase + 16 + ql;

  // Q fragments (MFMA B-operand): Q[q=ql][d=8g+e]
  const unsigned short* qpA = qkv + ((size_t)(b * 2048 + qrowA)) * 3072 + h * 64 + (g << 3);
  const unsigned short* qpB = qkv + ((size_t)(b * 2048 + qrowB)) * 3072 + h * 64 + (g << 3);
  const shortx8 qfA0 = *(const shortx8*)qpA;
  const shortx8 qfA1 = *(const shortx8*)(qpA + 32);
  const shortx8 qfB0 = *(const shortx8*)qpB;
  const shortx8 qfB1 = *(const shortx8*)(qpB + 32);

  f32x4 z = {0.f, 0.f, 0.f, 0.f};
  f32x4 accA[4], accB[4];
  #pragma unroll
  for (int c = 0; c < 4; ++c) { accA[c] = z; accB[c] = z; }
  float mA = -__builtin_inff(), lA = 0.f, mB = -__builtin_inff(), lB = 0.f;

  // staging: thread t -> row t>>3 (16 rows/pass, 4 passes), src chunk (t&7)^(row&7)
  const int srow = tid >> 3;
  const int sch = ((tid & 7) ^ (srow & 7)) << 3;
  const unsigned short* kb = qkv + ((size_t)(b * 2048 + srow)) * 3072 + 1024 + h * 64 + sch;
  const unsigned short* vb = vT + ((size_t)(h * 64 + srow)) * 4096 + b * 2048 + sch;

  #define STAGE(kv0_, bufi_)                                          \
    do {                                                              \
      unsigned short* Kd = &Ks[bufi_][w * 512];                       \
      unsigned short* Vd = &Vt[bufi_][w * 512];                       \
      _Pragma("unroll")                                               \
      for (int i = 0; i < 4; ++i) {                                   \
        gload16(kb + (size_t)((kv0_) + 16 * i) * 3072, Kd + i * 1024);\
        gload16(vb + (size_t)(16 * i) * 4096 + (kv0_), Vd + i * 1024);\
      }                                                               \
    } while (0)

  int buf = 0;
  STAGE(0, 0);
  for (int kvt = 0; kvt <= qt; ++kvt) {
    const bool last = (kvt == qt);
    if (!last) STAGE((kvt + 1) * 64, buf ^ 1);
    if (last) asm volatile("s_waitcnt vmcnt(0)" ::: "memory");
    else      asm volatile("s_waitcnt vmcnt(8)" ::: "memory");
    __builtin_amdgcn_sched_barrier(0);
    __builtin_amdgcn_s_barrier();
    __builtin_amdgcn_sched_barrier(0);
    const unsigned short* K = Ks[buf];
    const unsigned short* V = Vt[buf];
    const int kv0 = kvt * 64;

    // K fragments (shared by both q sub-tiles)
    shortx8 kf0[4], kf1[4];
    #pragma unroll
    for (int f = 0; f < 4; ++f) {
      const int r = 16 * f + ql;
      kf0[f] = *(const shortx8*)&K[r * 64 + (((g) ^ swz) << 3)];
      kf1[f] = *(const shortx8*)&K[r * 64 + (((4 + g) ^ swz) << 3)];
    }
    // QK^T both subs
    f32x4 sA[4], sB[4];
    #pragma unroll
    for (int f = 0; f < 4; ++f) {
      f32x4 t = MFMA16(kf0[f], qfA0, z);
      sA[f] = MFMA16(kf1[f], qfA1, t);
    }
    #pragma unroll
    for (int f = 0; f < 4; ++f) {
      f32x4 t = MFMA16(kf0[f], qfB0, z);
      sB[f] = MFMA16(kf1[f], qfB1, t);
    }
    // V fragments issued early (latency hides under softmax)
    shortx8 vf0[4], vf1[4];
    #pragma unroll
    for (int c = 0; c < 4; ++c) {
      const int r = 16 * c + ql;
      vf0[c] = *(const shortx8*)&V[r * 64 + (((g) ^ swz) << 3)];
      vf1[c] = *(const shortx8*)&V[r * 64 + (((4 + g) ^ swz) << 3)];
    }

    softmax_pack(sA, &Ps[w][0][0], ql, g, kv0, qrowA, last, mA, lA, accA);
    softmax_pack(sB, &Ps[w][1][0], ql, g, kv0, qrowB, last, mB, lB, accB);
    __builtin_amdgcn_sched_barrier(0);  // same-wave DS writes before reads
    shortx8 pfA0 = *(const shortx8*)&Ps[w][0][(g) * 128 + ql * 8];
    shortx8 pfA1 = *(const shortx8*)&Ps[w][0][(4 + g) * 128 + ql * 8];
    shortx8 pfB0 = *(const shortx8*)&Ps[w][1][(g) * 128 + ql * 8];
    shortx8 pfB1 = *(const shortx8*)&Ps[w][1][(4 + g) * 128 + ql * 8];
    #pragma unroll
    for (int c = 0; c < 4; ++c) {
      accA[c] = MFMA16(vf0[c], pfA0, accA[c]);
      accA[c] = MFMA16(vf1[c], pfA1, accA[c]);
      accB[c] = MFMA16(vf0[c], pfB0, accB[c]);
      accB[c] = MFMA16(vf1[c], pfB1, accB[c]);
    }
    __builtin_amdgcn_sched_barrier(0);
    __builtin_amdgcn_s_barrier();
    __builtin_amdgcn_sched_barrier(0);
    buf ^= 1;
  }
  #undef STAGE

  // epilogue: acc[c][j] = O^T[d=16c+4g+j][q=qrow]; pack 4 consecutive d -> 8B store
  const float invA = 1.f / lA;
  const float invB = 1.f / lB;
  unsigned short* oA = att + ((size_t)(b * 2048 + qrowA)) * 1024 + h * 64 + 4 * g;
  unsigned short* oB = att + ((size_t)(b * 2048 + qrowB)) * 1024 + h * 64 + 4 * g;
  #pragma unroll
  for (int c = 0; c < 4; ++c) {
    shortx4 a, bb;
    #pragma unroll
    for (int j = 0; j < 4; ++j) {
      a[j] = (short)f2bf(accA[c][j] * invA);
      bb[j] = (short)f2bf(accB[c][j] * invB);
    }
    *(shortx4*)&oA[16 * c] = a;
    *(shortx4*)&oB[16 * c] = bb;
  }
}

// ---------------- launch ----------------
extern "C" void kernel_launch(void* const* d_in, const int* in_sizes, int n_in,
                              void* d_out, int out_size, void* d_ws, size_t ws_size,
                              hipStream_t stream) {
  const float* x  = (const float*)d_in[0];
  const float* Wq = (const float*)d_in[1];
  const float* Wk = (const float*)d_in[2];
  const float* Wv = (const float*)d_in[3];
  const float* Wp = (const float*)d_in[4];
  const float* bp = (const float*)d_in[5];

  char* ws = (char*)d_ws;
  unsigned short* xb    = (unsigned short*)(ws);                        //  8 MB [4096][1024]
  unsigned short* wqkvT = (unsigned short*)(ws + (size_t)8  * 1048576); //  6 MB [3072][1024]
  unsigned short* wpT   = (unsigned short*)(ws + (size_t)14 * 1048576); //  2 MB [1024][1024]
  unsigned short* qkv   = (unsigned short*)(ws + (size_t)16 * 1048576); // 24 MB [4096][3072]
  unsigned short* vT    = (unsigned short*)(ws + (size_t)40 * 1048576); //  8 MB [1024][4096]
  unsigned short* att   = (unsigned short*)(ws + (size_t)48 * 1048576); //  8 MB [4096][1024]

  cvt_x<<<dim3(4096), dim3(256), 0, stream>>>(x, xb, 1048576);
  transpose_w4<<<dim3(32, 32, 4), dim3(256), 0, stream>>>(Wq, Wk, Wv, Wp, wqkvT, wpT);
  gemm_bt<<<dim3(24, 32), dim3(256), 0, stream>>>(xb, wqkvT, qkv, nullptr, nullptr,
                                                  4096, 3072, 1024);
  transpose_v<<<dim3(16, 64), dim3(256), 0, stream>>>(qkv, vT);
  attn_fwd<<<dim3(32, 32, 1), dim3(128), 0, stream>>>(qkv, vT, att);
  gemm_bt<<<dim3(8, 32), dim3(256), 0, stream>>>(att, wpT, nullptr, (float*)d_out, bp,
                                                 4096, 1024, 1024);
}